// Round 1
// baseline (351.125 us; speedup 1.0000x reference)
//
#include <hip/hip_runtime.h>

#define NF 32  // IN_FEATS == OUT_FEATS == 32

// Stage 1: in-degree histogram over dst (self-loop added later as +1).
__global__ void deg_kernel(const int* __restrict__ dst, int* __restrict__ deg, int n_edges) {
    int i = blockIdx.x * blockDim.x + threadIdx.x;
    if (i < n_edges) atomicAdd(&deg[dst[i]], 1);
}

// Stage 2: h[n] = (x[n] * rsqrt(deg[n])) @ W^T ; agg initialized to h (self-loop term).
// 256 threads = 8 nodes x 32 output feats. W transposed into LDS: sWt[i*32+o] = W[o*32+i]
// so the inner read sWt[i*32+o] is bank-conflict-free (o spans 32 banks).
__global__ void proj_kernel(const float* __restrict__ x, const float* __restrict__ W,
                            const int* __restrict__ deg, float* __restrict__ isd,
                            float* __restrict__ h, float* __restrict__ agg, int n_nodes) {
    __shared__ float sWt[NF * NF];
    int t = threadIdx.x;
    for (int k = t; k < NF * NF; k += 256) sWt[k] = W[(k & 31) * NF + (k >> 5)];
    __syncthreads();
    int node = blockIdx.x * 8 + (t >> 5);
    int o = t & 31;
    if (node < n_nodes) {
        float s = rsqrtf((float)(deg[node] + 1));  // +1 self-loop; always >=1 so no clamp needed
        if (o == 0) isd[node] = s;
        const float* xr = x + (size_t)node * NF;
        float acc = 0.f;
#pragma unroll
        for (int i = 0; i < NF; i++) acc = fmaf(xr[i], sWt[i * NF + o], acc);
        float v = acc * s;
        int idx = node * NF + o;
        h[idx] = v;
        agg[idx] = v;  // self-loop contribution
    }
}

// Stage 3: scatter-add. One thread per (edge, feat).
__global__ void scatter_kernel(const int* __restrict__ src, const int* __restrict__ dst,
                               const float* __restrict__ h, float* __restrict__ agg,
                               int n_edges) {
    long long idx = (long long)blockIdx.x * blockDim.x + threadIdx.x;
    if (idx < (long long)n_edges * NF) {
        int e = (int)(idx >> 5);
        int o = (int)(idx & 31);
        int s = src[e];
        int d = dst[e];
        atomicAdd(&agg[d * NF + o], h[s * NF + o]);
    }
}

// Stage 4: out = relu(agg * isd + bias)
__global__ void finalize_kernel(const float* __restrict__ agg, const float* __restrict__ isd,
                                const float* __restrict__ bias, float* __restrict__ out,
                                int n_nodes) {
    int idx = blockIdx.x * blockDim.x + threadIdx.x;
    if (idx < n_nodes * NF) {
        int n = idx >> 5;
        int o = idx & 31;
        float v = fmaf(agg[idx], isd[n], bias[o]);
        out[idx] = fmaxf(v, 0.f);
    }
}

extern "C" void kernel_launch(void* const* d_in, const int* in_sizes, int n_in,
                              void* d_out, int out_size, void* d_ws, size_t ws_size,
                              hipStream_t stream) {
    const float* feature = (const float*)d_in[0];
    const int*   src     = (const int*)d_in[1];
    const int*   dst     = (const int*)d_in[2];
    const float* W       = (const float*)d_in[3];
    const float* bias    = (const float*)d_in[4];
    float* out = (float*)d_out;

    int n_nodes = in_sizes[0] / NF;
    int n_edges = in_sizes[1];

    char* ws = (char*)d_ws;
    size_t off = 0;
    int* deg = (int*)(ws + off);
    off += ((size_t)n_nodes * 4 + 255) & ~(size_t)255;
    float* isd = (float*)(ws + off);
    off += ((size_t)n_nodes * 4 + 255) & ~(size_t)255;
    float* h = (float*)(ws + off);
    off += ((size_t)n_nodes * NF * 4 + 255) & ~(size_t)255;
    float* agg = (float*)(ws + off);

    hipMemsetAsync(deg, 0, (size_t)n_nodes * 4, stream);

    deg_kernel<<<(n_edges + 255) / 256, 256, 0, stream>>>(dst, deg, n_edges);

    proj_kernel<<<(n_nodes + 7) / 8, 256, 0, stream>>>(feature, W, deg, isd, h, agg, n_nodes);

    long long total = (long long)n_edges * NF;
    scatter_kernel<<<(int)((total + 255) / 256), 256, 0, stream>>>(src, dst, h, agg, n_edges);

    finalize_kernel<<<(n_nodes * NF + 255) / 256, 256, 0, stream>>>(agg, isd, bias, out, n_nodes);
}